// Round 6
// baseline (290.339 us; speedup 1.0000x reference)
//
#include <hip/hip_runtime.h>
#include <hip/hip_fp16.h>

// ImportancePooling: N=100000, K=32, D=64.
// Round-9: byte-reduction round (kernel is L2-miss-bytes bound @ ~3.75 TB/s).
//  - REMOVED all nontemporal hints on headers/output: round-5 counters showed
//    nt stores (2 interleaved 16B) caused partial-line writes + RMW
//    (WRITE +30.8MB, FETCH +19.1MB). Plain stores write-combine in L2.
//  - 2-phase feature split: phase p gathers the p-th 64B half of each row
//    (features 32p..32p+31). Instantaneous working set 12.8 -> 6.4 MB,
//    cutting L2 capacity misses; compulsory per-XCD fills unchanged.
//    Headers stay in registers across phases; sched_barrier + s_barrier
//    keep the phases temporally separated.
//  - 8 nodes per wave: lane l -> node (l>>3), 8B block (l&7) of the 64B
//    half-row; one global_load_dwordx2 pulls 8 random rows x 64B = 512B.
//  - headers loaded transposed ([k][node]) so per-k (w,idx) broadcast is a
//    compile-time-addressed ds_bpermute.

#define K_NBR 32
#define D_FEAT 64

typedef float f32x4 __attribute__((ext_vector_type(4)));
typedef unsigned int u32x2 __attribute__((ext_vector_type(2)));

static __device__ __forceinline__ __half2 u32_as_h2(unsigned int u) {
  __half2 h;
  __builtin_memcpy(&h, &u, 4);
  return h;
}

static __device__ __forceinline__ unsigned int h2_as_u32(__half2 h) {
  unsigned int u;
  __builtin_memcpy(&u, &h, 4);
  return u;
}

__global__ __launch_bounds__(256) void ImportancePooling_28424093564958_convert(
    const f32x4* __restrict__ x4, u32x2* __restrict__ xh4, int n4) {
  const int i = blockIdx.x * blockDim.x + threadIdx.x;
  if (i < n4) {
    const f32x4 v = __builtin_nontemporal_load(&x4[i]);  // fp32 x: read-once
    const __half2 a = __floats2half2_rn(v.x, v.y);
    const __half2 b = __floats2half2_rn(v.z, v.w);
    u32x2 u;
    u.x = h2_as_u32(a);
    u.y = h2_as_u32(b);
    xh4[i] = u;  // regular store: gather kernel wants this in L2
  }
}

__global__ __launch_bounds__(256, 8) void ImportancePooling_28424093564958_kernel(
    const u32x2* __restrict__ xh2,      // [N, 16] u32x2 view of fp16 x rows (128 B/row)
    const int* __restrict__ neighbors,  // [N, 32]
    const float* __restrict__ weights,  // [N, 32]
    f32x4* __restrict__ out4,           // [N, 16] f32x4 view of out
    int Nw) {                           // Nw = N/8 (waves)
  const int wave_id = (int)((blockIdx.x * blockDim.x + threadIdx.x) >> 6);
  const int lane = threadIdx.x & 63;
  if (wave_id >= Nw) return;

  const int g = lane >> 3;   // node sub-index 0..7
  const int f = lane & 7;    // 8B block within the 64B half-row
  const int gb4 = g << 2;    // bpermute byte base for node g
  const long hbase = (long)wave_id * 256;  // 8 nodes * 32 header elements

  // Transposed header load: reg j, lane l holds header[(l&7)*32 + j*8 + (l>>3)]
  // i.e. node (l&7), neighbor k = j*8 + (l>>3). Plain loads: L1/L2 serve the
  // strided halves of each 64B line across the 4 loads.
  int wb[4], nb[4];
  {
    const long e0 = hbase + f * 32 + g;
    wb[0] = __float_as_int(weights[e0]);
    wb[1] = __float_as_int(weights[e0 + 8]);
    wb[2] = __float_as_int(weights[e0 + 16]);
    wb[3] = __float_as_int(weights[e0 + 24]);
    nb[0] = neighbors[e0];
    nb[1] = neighbors[e0 + 8];
    nb[2] = neighbors[e0 + 16];
    nb[3] = neighbors[e0 + 24];
  }

  // wsum for node (lane&7): per-lane partial over 4 k's, then butterfly over
  // the 8 lanes sharing (lane&7) (xor 8/16/32 preserves the &7 class).
  float s = __int_as_float(wb[0]) + __int_as_float(wb[1]) +
            __int_as_float(wb[2]) + __int_as_float(wb[3]);
  s += __shfl_xor(s, 8, 64);
  s += __shfl_xor(s, 16, 64);
  s += __shfl_xor(s, 32, 64);
  const float invp = (s > 0.0f) ? (1.0f / s) : 1.0f;
  // lane needs inv of node (lane>>3); it lives at lane g (g<8 -> g&7==g).
  const float inv = __int_as_float(
      __builtin_amdgcn_ds_bpermute(gb4, __float_as_int(invp)));

  // Two feature phases: p=0 -> features 0..31 (first 64B of each row),
  // p=1 -> features 32..63. Working set per phase = 6.4 MB.
#pragma unroll
  for (int p = 0; p < 2; ++p) {
    float a0 = 0.0f, a1 = 0.0f, a2 = 0.0f, a3 = 0.0f;
#pragma unroll
    for (int k = 0; k < K_NBR; ++k) {
      // (w, idx) of node (l>>3), neighbor k sits at lane ((k&7)<<3) | (l>>3)
      // of register (k>>3) -- all compile-time under full unroll.
      const int addr = ((k & 7) << 5) + gb4;
      const float wk =
          __int_as_float(__builtin_amdgcn_ds_bpermute(addr, wb[k >> 3]));
      const int idx = __builtin_amdgcn_ds_bpermute(addr, nb[k >> 3]);
      // 8 rows x 64B = 512B per wave instruction; 16 u32x2 per 128B row.
      const u32x2 h = xh2[(unsigned)idx * 16u + (unsigned)(p * 8 + f)];
      const __half2 p0 = u32_as_h2(h.x);
      const __half2 p1 = u32_as_h2(h.y);
      a0 = fmaf(wk, __low2float(p0), a0);   // v_fma_mix_f32
      a1 = fmaf(wk, __high2float(p0), a1);
      a2 = fmaf(wk, __low2float(p1), a2);
      a3 = fmaf(wk, __high2float(p1), a3);
    }
    f32x4 o;
    o.x = a0 * inv;
    o.y = a1 * inv;
    o.z = a2 * inv;
    o.w = a3 * inv;
    // node (wave_id*8+g), phase p, block f -> f32x4 index node*16 + p*8 + f.
    out4[(unsigned)wave_id * 128u + (unsigned)g * 16u + (unsigned)(p * 8 + f)] = o;
    // Keep phases temporally separated: pin instruction order (compiler) and
    // re-align the block's 4 waves (hardware) at the phase boundary.
    __builtin_amdgcn_sched_barrier(0);
    if (p == 0) __builtin_amdgcn_s_barrier();
  }
}

// Fallback (ws too small / N not divisible by 8): direct fp32 gather.
__global__ __launch_bounds__(256) void ImportancePooling_28424093564958_f32(
    const float* __restrict__ x, const int* __restrict__ neighbors,
    const float* __restrict__ weights, float* __restrict__ out, int N) {
  const int wave_id = (int)((blockIdx.x * blockDim.x + threadIdx.x) >> 6);
  const int lane = threadIdx.x & 63;
  if (wave_id >= N) return;
  const long hbase = (long)wave_id * K_NBR;
  int packed;
  if (lane < K_NBR) {
    packed = __float_as_int(weights[hbase + lane]);
  } else {
    packed = neighbors[hbase + (lane - K_NBR)];
  }
  float acc = 0.0f, wsum = 0.0f;
#pragma unroll
  for (int k = 0; k < K_NBR; ++k) {
    const float wk = __int_as_float(__builtin_amdgcn_readlane(packed, k));
    const int idx = __builtin_amdgcn_readlane(packed, K_NBR + k);
    wsum += wk;
    acc += wk * x[(long)idx * D_FEAT + lane];
  }
  const float inv = (wsum > 0.0f) ? (1.0f / wsum) : 1.0f;
  out[(long)wave_id * D_FEAT + lane] = acc * inv;
}

extern "C" void kernel_launch(void* const* d_in, const int* in_sizes, int n_in,
                              void* d_out, int out_size, void* d_ws, size_t ws_size,
                              hipStream_t stream) {
  const float* x = (const float*)d_in[0];
  const int* neighbors = (const int*)d_in[1];
  const float* weights = (const float*)d_in[2];

  const int N = in_sizes[0] / D_FEAT;  // 100000
  const size_t xh_bytes = (size_t)N * D_FEAT * sizeof(__half);

  if (ws_size >= xh_bytes && (N % 8) == 0) {
    const int n4 = N * D_FEAT / 4;
    ImportancePooling_28424093564958_convert<<<(n4 + 255) / 256, 256, 0, stream>>>(
        (const f32x4*)x, (u32x2*)d_ws, n4);

    const int Nw = N / 8;
    const int block = 256;  // 4 waves/block
    const int grid = (Nw * 64 + block - 1) / block;
    ImportancePooling_28424093564958_kernel<<<grid, block, 0, stream>>>(
        (const u32x2*)d_ws, neighbors, weights, (f32x4*)d_out, Nw);
  } else {
    const int block = 256;
    const int grid = (N * 64 + block - 1) / block;
    ImportancePooling_28424093564958_f32<<<grid, block, 0, stream>>>(
        x, neighbors, weights, (float*)d_out, N);
  }
}

// Round 8
// 136.508 us; speedup vs baseline: 2.1269x; 2.1269x over previous
//
#include <hip/hip_runtime.h>
#include <hip/hip_fp16.h>

// ImportancePooling: N=100000, K=32, D=64.
// Round-11 (= round-10 resubmit; container infra failure, kernel untested).
// Revert to round-0 structure (best: 49.2us main, byte-optimal writes), plus:
//  - batch-8 gather: 8 (w,idx) bpermutes -> 8 independent global_load_dword
//    issued back-to-back -> 16 fmas. Guarantees >=8 outstanding misses/wave
//    (round-6 showed the miss path sustains 4.25 TB/s with more MLP; round-0
//    ran at only 3.8).
//  - nontemporal LOADS on read-once headers (keeps 25.6 MB of stream out of
//    the 4MB/XCD L2 that caches the gather-hot staged array). NT STORES ARE
//    FORBIDDEN: rounds 5/6 showed they defeat write-combining (+30..+320 MB).
// Geometry (round-0): lanes 0..31 = node A, 32..63 = node B; each lane owns
// 2 features (half2); one global_load_dword serves two neighbor rows.

#define K_NBR 32
#define D_FEAT 64

typedef float f32x4 __attribute__((ext_vector_type(4)));
typedef unsigned int u32x2 __attribute__((ext_vector_type(2)));

static __device__ __forceinline__ unsigned int h2_as_u32(__half2 h) {
  unsigned int u;
  __builtin_memcpy(&u, &h, 4);
  return u;
}

__global__ __launch_bounds__(256) void ImportancePooling_28424093564958_convert(
    const f32x4* __restrict__ x4, u32x2* __restrict__ xh4, int n4) {
  const int i = blockIdx.x * blockDim.x + threadIdx.x;
  if (i < n4) {
    const f32x4 v = __builtin_nontemporal_load(&x4[i]);  // fp32 x: read-once
    const __half2 a = __floats2half2_rn(v.x, v.y);
    const __half2 b = __floats2half2_rn(v.z, v.w);
    u32x2 u;
    u.x = h2_as_u32(a);
    u.y = h2_as_u32(b);
    xh4[i] = u;  // plain store: gather kernel wants this resident in L2
  }
}

__global__ __launch_bounds__(256) void ImportancePooling_28424093564958_kernel(
    const __half2* __restrict__ xh2,    // [N, 32] half2 view of staged fp16 x
    const int* __restrict__ neighbors,  // [N, 32]
    const float* __restrict__ weights,  // [N, 32]
    float2* __restrict__ out2,          // [N, 32] float2 view of out
    int Nw) {                           // Nw = N/2 (waves)
  const int wave_id = (int)((blockIdx.x * blockDim.x + threadIdx.x) >> 6);
  const int lane = threadIdx.x & 63;
  if (wave_id >= Nw) return;

  // Header: lanes 0..31 = node A's 32 (w, idx), lanes 32..63 = node B's.
  // Read-once, coalesced -> nontemporal (scalar types: builtin-legal).
  const long hbase = (long)wave_id * 64;
  const int w_bits =
      __float_as_int(__builtin_nontemporal_load(&weights[hbase + lane]));
  const int nb = __builtin_nontemporal_load(&neighbors[hbase + lane]);

  // Per-half wsum: xor offsets <=16 never cross the 32-lane half boundary.
  float wsum = __int_as_float(w_bits);
  #pragma unroll
  for (int off = 16; off >= 1; off >>= 1) wsum += __shfl_xor(wsum, off, 64);
  const float inv = (wsum > 0.0f) ? (1.0f / wsum) : 1.0f;

  const int vbase = (lane & 32) << 2;  // bpermute byte base: 0 or 128
  const int sub = lane & 31;           // half2 column within the row

  float accx = 0.0f, accy = 0.0f;
  // Batch-8: address phase (16 bpermutes), issue phase (8 independent
  // global_load_dword back-to-back), consume phase (16 v_fma_mix).
  #pragma unroll
  for (int kb = 0; kb < K_NBR; kb += 8) {
    float wk[8];
    int idx[8];
    #pragma unroll
    for (int j = 0; j < 8; ++j) {
      const int a = vbase + 4 * (kb + j);
      wk[j] = __int_as_float(__builtin_amdgcn_ds_bpermute(a, w_bits));
      idx[j] = __builtin_amdgcn_ds_bpermute(a, nb);
    }
    __half2 h[8];
    #pragma unroll
    for (int j = 0; j < 8; ++j) {
      h[j] = xh2[(long)idx[j] * (D_FEAT / 2) + sub];
    }
    #pragma unroll
    for (int j = 0; j < 8; ++j) {
      accx = fmaf(wk[j], __low2float(h[j]), accx);   // v_fma_mix_f32
      accy = fmaf(wk[j], __high2float(h[j]), accy);
    }
  }

  float2 o;
  o.x = accx * inv;
  o.y = accy * inv;
  // out2 row for node 2w+half starts at (2w+half)*32 -> index = w*64 + lane.
  // Plain store: wave writes 512B contiguous, write-combines to full lines.
  out2[hbase + lane] = o;
}

// Fallback (ws too small): direct fp32 gather, one node per wave.
__global__ __launch_bounds__(256) void ImportancePooling_28424093564958_f32(
    const float* __restrict__ x, const int* __restrict__ neighbors,
    const float* __restrict__ weights, float* __restrict__ out, int N) {
  const int wave_id = (int)((blockIdx.x * blockDim.x + threadIdx.x) >> 6);
  const int lane = threadIdx.x & 63;
  if (wave_id >= N) return;
  const long hbase = (long)wave_id * K_NBR;
  int packed;
  if (lane < K_NBR) {
    packed = __float_as_int(weights[hbase + lane]);
  } else {
    packed = neighbors[hbase + (lane - K_NBR)];
  }
  float acc = 0.0f, wsum = 0.0f;
  #pragma unroll
  for (int k = 0; k < K_NBR; ++k) {
    const float wk = __int_as_float(__builtin_amdgcn_readlane(packed, k));
    const int idx = __builtin_amdgcn_readlane(packed, K_NBR + k);
    wsum += wk;
    acc += wk * x[(long)idx * D_FEAT + lane];
  }
  const float inv = (wsum > 0.0f) ? (1.0f / wsum) : 1.0f;
  out[(long)wave_id * D_FEAT + lane] = acc * inv;
}

extern "C" void kernel_launch(void* const* d_in, const int* in_sizes, int n_in,
                              void* d_out, int out_size, void* d_ws, size_t ws_size,
                              hipStream_t stream) {
  const float* x = (const float*)d_in[0];
  const int* neighbors = (const int*)d_in[1];
  const float* weights = (const float*)d_in[2];

  const int N = in_sizes[0] / D_FEAT;  // 100000
  const size_t xh_bytes = (size_t)N * D_FEAT * sizeof(__half);

  if (ws_size >= xh_bytes && (N % 2) == 0) {
    const int n4 = N * D_FEAT / 4;
    ImportancePooling_28424093564958_convert<<<(n4 + 255) / 256, 256, 0, stream>>>(
        (const f32x4*)x, (u32x2*)d_ws, n4);

    const int Nw = N / 2;
    const int block = 256;  // 4 waves/block
    const int grid = (Nw * 64 + block - 1) / block;
    ImportancePooling_28424093564958_kernel<<<grid, block, 0, stream>>>(
        (const __half2*)d_ws, neighbors, weights, (float2*)d_out, Nw);
  } else {
    const int block = 256;
    const int grid = (N * 64 + block - 1) / block;
    ImportancePooling_28424093564958_f32<<<grid, block, 0, stream>>>(
        x, neighbors, weights, (float*)d_out, N);
  }
}